// Round 5
// baseline (2016.666 us; speedup 1.0000x reference)
//
#include <hip/hip_runtime.h>
#include <hip/hip_bf16.h>

typedef _Float16 f16;
typedef __attribute__((ext_vector_type(8))) _Float16 f16x8;  // MFMA A/B frag
typedef __attribute__((ext_vector_type(4))) float f4v;       // 16x16 acc
typedef __attribute__((ext_vector_type(16))) float f32x16;   // 32x32 acc

constexpr int NSEQ = 4096;
constexpr int EMB  = 1024;
constexpr int NH   = 16;
constexpr int HD   = 32;       // head dim
constexpr int NL   = 6;
constexpr int HV   = NH * HD;  // 512
constexpr int FF   = 2 * EMB;  // 2048
constexpr int QKVW = 3 * HV;   // 1536 (q|k|v concatenated per row)

// direct global->LDS DMA, 16B per lane (dest = uniform base + lane*16)
#define GLDS16(gp, lp) __builtin_amdgcn_global_load_lds( \
    (const __attribute__((address_space(1))) void*)(const void*)(gp), \
    (__attribute__((address_space(3))) void*)(void*)(lp), 16, 0, 0)

// pack two f32 -> 2xf16 (RTZ) as a dword
__device__ __forceinline__ unsigned pk2h(float a, float b) {
  auto h = __builtin_amdgcn_cvt_pkrtz(a, b);   // __fp16 ext_vector(2)
  unsigned d; __builtin_memcpy(&d, &h, 4);
  return d;
}

// ---------------- embedding: z = table[ctx] + pos; also f16 copy ----------
__global__ __launch_bounds__(256) void embed_kernel(const int* __restrict__ ctx,
    const float* __restrict__ table, const float* __restrict__ pos,
    float* __restrict__ z, f16* __restrict__ zh){
  int t = blockIdx.x * 256 + threadIdx.x;
  int n = t >> 8;
  int e = (t & 255) << 2;
  float4 a = *reinterpret_cast<const float4*>(table + (size_t)ctx[n] * EMB + e);
  float4 b = *reinterpret_cast<const float4*>(pos   + (size_t)n * EMB + e);
  float4 r = {a.x + b.x, a.y + b.y, a.z + b.z, a.w + b.w};
  *reinterpret_cast<float4*>(z + (size_t)n * EMB + e) = r;
  f16 o[4] = {(f16)r.x, (f16)r.y, (f16)r.z, (f16)r.w};
  uint2 u; __builtin_memcpy(&u, o, 8);
  *reinterpret_cast<uint2*>(zh + (size_t)n * EMB + e) = u;
}

// ------------- transpose-convert: out[n*K + k] = (f16)in[k*N + n] ----------
__global__ __launch_bounds__(256) void convT_kernel(const float* __restrict__ in,
    f16* __restrict__ out, int K, int N, long sInZ, long sOutZ){
  __shared__ float t[32][33];
  in  += (size_t)blockIdx.z * sInZ;
  out += (size_t)blockIdx.z * sOutZ;
  int k0 = blockIdx.x * 32, n0 = blockIdx.y * 32;
  int r = threadIdx.x >> 5, c = threadIdx.x & 31;
  #pragma unroll
  for (int i = 0; i < 4; i++)
    t[r + i*8][c] = in[(size_t)(k0 + r + i*8) * N + n0 + c];
  __syncthreads();
  #pragma unroll
  for (int i = 0; i < 4; i++)
    out[(size_t)(n0 + r + i*8) * K + k0 + c] = (f16)t[c][r + i*8];
}

// ---------------- MFMA GEMM: C = act(A @ Bt^T + bias) + res ----------------
// A: f16 [M x K] row-major. Bt: f16 [N x K] row-major (B transposed).
// 128x128 tile, BK=32, 4 waves (2x2 of 64x64). 16x16x32 f16 MFMA.
// Staging: global_load_lds width=16, linear [128][32] LDS.
template<typename CT>
__global__ __launch_bounds__(256) void gemm_mfma(
    const f16* __restrict__ A, const f16* __restrict__ Bt, CT* C,
    const float* __restrict__ bias, const float* res,
    int K, int Nc, int leaky)
{
  __shared__ f16 Ash[128 * 32];
  __shared__ f16 Bsh[128 * 32];
  int tid = threadIdx.x;
  int lane = tid & 63, w = tid >> 6;
  int wm = w & 1, wn = w >> 1;
  int l16 = lane & 15, quad = lane >> 4;
  int row0 = blockIdx.y * 128, col0 = blockIdx.x * 128;

  f4v acc[4][4];
  #pragma unroll
  for (int i = 0; i < 4; i++)
    #pragma unroll
    for (int j = 0; j < 4; j++) acc[i][j] = {0.f, 0.f, 0.f, 0.f};

  int srow = lane >> 2;          // 0..15
  int scol = (lane & 3) * 8;     // 0/8/16/24
  const f16* gA0 = A  + (size_t)(row0 + w*32      + srow) * K + scol;
  const f16* gA1 = A  + (size_t)(row0 + w*32 + 16 + srow) * K + scol;
  const f16* gB0 = Bt + (size_t)(col0 + w*32      + srow) * K + scol;
  const f16* gB1 = Bt + (size_t)(col0 + w*32 + 16 + srow) * K + scol;
  f16* lA0 = Ash + (w*2    ) * 512;
  f16* lA1 = Ash + (w*2 + 1) * 512;
  f16* lB0 = Bsh + (w*2    ) * 512;
  f16* lB1 = Bsh + (w*2 + 1) * 512;

  for (int k0 = 0; k0 < K; k0 += 32) {
    __syncthreads();                       // prior tile fully consumed
    GLDS16(gA0 + k0, lA0);
    GLDS16(gA1 + k0, lA1);
    GLDS16(gB0 + k0, lB0);
    GLDS16(gB1 + k0, lB1);
    __syncthreads();                       // vmcnt(0) drain: tile resident
    f16x8 af[4], bf[4];
    #pragma unroll
    for (int mt = 0; mt < 4; mt++)
      af[mt] = *reinterpret_cast<const f16x8*>(&Ash[(wm*64 + mt*16 + l16) * 32 + quad*8]);
    #pragma unroll
    for (int nt = 0; nt < 4; nt++)
      bf[nt] = *reinterpret_cast<const f16x8*>(&Bsh[(wn*64 + nt*16 + l16) * 32 + quad*8]);
    #pragma unroll
    for (int mt = 0; mt < 4; mt++)
      #pragma unroll
      for (int nt = 0; nt < 4; nt++)
        acc[mt][nt] = __builtin_amdgcn_mfma_f32_16x16x32_f16(af[mt], bf[nt], acc[mt][nt], 0, 0, 0);
  }

  #pragma unroll
  for (int mt = 0; mt < 4; mt++) {
    #pragma unroll
    for (int nt = 0; nt < 4; nt++) {
      int ccol = col0 + wn*64 + nt*16 + l16;
      float bv = bias ? bias[ccol] : 0.f;
      #pragma unroll
      for (int reg = 0; reg < 4; reg++) {
        int crow = row0 + wm*64 + mt*16 + quad*4 + reg;
        float v = acc[mt][nt][reg] + bv;
        if (leaky) v = v > 0.f ? v : 0.01f * v;
        if (res)   v += res[(size_t)crow * Nc + ccol];
        if constexpr (sizeof(CT) == 2) C[(size_t)crow * Nc + ccol] = (f16)v;
        else                           C[(size_t)crow * Nc + ccol] = v;
      }
    }
  }
}

// ---------------- MFMA flash attention, 32x32 transposed-score --------------
// qkv: f16 [N][1536]. O: f16 [N][512]. Block = 128 thr = 2 waves x 32 queries.
// 128-key tiles, double-buffered K/V LDS, ONE barrier per tile.
// S^T chunk c (32 keys x 32 q) = K·Q via 2x mfma_32x32x16:
//   A: lane(l31,h) = K[c*32+l31][sub*16+h*8+j]; B: Q[q0+l31][sub*16+h*8+j].
//   C/D: col=lane&31 (query), row = (reg&3)+8*(reg>>2)+4*(lane>>5) (key).
// P stays in registers: cvt_pkrtz pack -> one shfl_xor(32) half-exchange
// builds the PV B-operand directly (perfect permutation, no LDS round-trip).
// O^T = V^T·P accumulated in 2 chains (A/B) for MFMA ILP.
__global__ __launch_bounds__(128) void attn_mfma(const f16* __restrict__ qkv,
    f16* __restrict__ O)
{
  __shared__ f16 Ks[2][128][40];   // [key][dim]  stride 80B
  __shared__ f16 Vt[2][32][136];   // [dim][key]  stride 272B
  int tid = threadIdx.x;
  int lane = tid & 63, w = tid >> 6;       // 2 waves
  int l31 = lane & 31, h = lane >> 5;
  int hd = blockIdx.y;
  int q0 = blockIdx.x * 64 + w * 32;
  const float sc = 0.17677669529663687f * 1.4426950408889634f; // 1/sqrt(32)*log2e

  // Q B-frags: qf{0,1}[j] = Q[q0+l31][sub*16 + h*8 + j] * sc
  f16x8 qf0, qf1;
  {
    const f16* qp = qkv + (size_t)(q0 + l31) * QKVW + hd * HD + h * 8;
    union { uint4 u; f16 e[8]; } a, b;
    a.u = *reinterpret_cast<const uint4*>(qp);
    b.u = *reinterpret_cast<const uint4*>(qp + 16);
    #pragma unroll
    for (int i = 0; i < 8; i++) {
      a.e[i] = (f16)((float)a.e[i] * sc);
      b.e[i] = (f16)((float)b.e[i] * sc);
    }
    __builtin_memcpy(&qf0, a.e, 16);
    __builtin_memcpy(&qf1, b.e, 16);
  }

  float m_ = -1e30f, lsum = 0.f;           // per-lane state for query l31
  f32x16 oaccA, oaccB, zz;
  #pragma unroll
  for (int i = 0; i < 16; i++) { oaccA[i] = 0.f; oaccB[i] = 0.f; zz[i] = 0.f; }

  int vkp = tid & 63;                      // V staging: key pair 0..63
  uint4 kr0, kr1, kr2, kr3, vr0, vr1, vr2, vr3;

  auto LOADT = [&](int kt) {               // issue global loads (reg staging)
    const f16* kp = qkv + (size_t)(kt + tid) * QKVW + HV + hd * HD;
    const uint4* kq = reinterpret_cast<const uint4*>(kp);
    kr0 = kq[0]; kr1 = kq[1]; kr2 = kq[2]; kr3 = kq[3];
    const f16* vp = qkv + (size_t)(kt + 2*vkp) * QKVW + 2*HV + hd * HD + w * 16;
    vr0 = *reinterpret_cast<const uint4*>(vp);
    vr1 = *reinterpret_cast<const uint4*>(vp + QKVW);
    vr2 = *reinterpret_cast<const uint4*>(vp + 8);
    vr3 = *reinterpret_cast<const uint4*>(vp + QKVW + 8);
  };
  auto WRITET = [&](int b) {               // regs -> LDS (vmcnt wait here)
    *reinterpret_cast<uint4*>(&Ks[b][tid][0])  = kr0;
    *reinterpret_cast<uint4*>(&Ks[b][tid][8])  = kr1;
    *reinterpret_cast<uint4*>(&Ks[b][tid][16]) = kr2;
    *reinterpret_cast<uint4*>(&Ks[b][tid][24]) = kr3;
    union { uint4 u; f16 e[8]; } c0, c1, c2, c3;
    c0.u = vr0; c1.u = vr1; c2.u = vr2; c3.u = vr3;
    #pragma unroll
    for (int i = 0; i < 8; i++) {          // pack key pair -> one dword
      f16 p0[2] = {c0.e[i], c1.e[i]};
      unsigned d0; __builtin_memcpy(&d0, p0, 4);
      *reinterpret_cast<unsigned*>(&Vt[b][w*16 + i][2*vkp]) = d0;
      f16 p1[2] = {c2.e[i], c3.e[i]};
      unsigned d1; __builtin_memcpy(&d1, p1, 4);
      *reinterpret_cast<unsigned*>(&Vt[b][w*16 + 8 + i][2*vkp]) = d1;
    }
  };

  LOADT(0);
  WRITET(0);
  __syncthreads();
  int cur = 0;

  for (int kt = 0; kt < NSEQ; kt += 128) {
    LOADT((kt + 128) & (NSEQ - 1));        // issue next tile now (T14)

    // ---- S^T: 4 chunks x 2 serial MFMA ----
    f32x16 s0, s1, s2, s3;
    __builtin_amdgcn_s_setprio(1);
    #define SCHUNK(sv, c) { \
      f16x8 a0 = *reinterpret_cast<const f16x8*>(&Ks[cur][(c)*32 + l31][h*8]); \
      f16x8 a1 = *reinterpret_cast<const f16x8*>(&Ks[cur][(c)*32 + l31][16 + h*8]); \
      sv = __builtin_amdgcn_mfma_f32_32x32x16_f16(a0, qf0, zz, 0, 0, 0); \
      sv = __builtin_amdgcn_mfma_f32_32x32x16_f16(a1, qf1, sv, 0, 0, 0); }
    SCHUNK(s0, 0) SCHUNK(s1, 1) SCHUNK(s2, 2) SCHUNK(s3, 3)
    #undef SCHUNK
    __builtin_amdgcn_s_setprio(0);

    // ---- tile max: per-chunk trees + cross-half (1 shfl) ----
    auto cmax = [](const f32x16& s) {
      float a = fmaxf(fmaxf(s[0], s[1]),   fmaxf(s[2], s[3]));
      float b = fmaxf(fmaxf(s[4], s[5]),   fmaxf(s[6], s[7]));
      float c = fmaxf(fmaxf(s[8], s[9]),   fmaxf(s[10], s[11]));
      float d = fmaxf(fmaxf(s[12], s[13]), fmaxf(s[14], s[15]));
      return fmaxf(fmaxf(a, b), fmaxf(c, d));
    };
    float tm = fmaxf(fmaxf(cmax(s0), cmax(s1)), fmaxf(cmax(s2), cmax(s3)));
    tm = fmaxf(tm, __shfl_xor(tm, 32));
    if (!__all(tm <= m_)) {                // defer-max: skip is bit-exact
      float mN = fmaxf(m_, tm);
      float corr = __builtin_amdgcn_exp2f(m_ - mN);   // first tile: 0
      m_ = mN; lsum *= corr;
      #pragma unroll
      for (int i = 0; i < 16; i++) { oaccA[i] *= corr; oaccB[i] *= corr; }
    }

    // ---- per chunk: exp2, pack, half-exchange, PV MFMA ----
    float ls = 0.f;
    // Lane (l31,h') holds keys r+8g+4h' (g=reg>>2). Dest B-frag sub s needs
    // partner groups {h,2+h}; we send own groups {1-h,3-h}; shfl_xor(32).
    #define PVCHUNK(sv, c, oacc) { \
      float pv[16]; \
      _Pragma("unroll") \
      for (int r_ = 0; r_ < 16; r_++) { \
        pv[r_] = __builtin_amdgcn_exp2f(sv[r_] - m_); ls += pv[r_]; } \
      unsigned d00 = pk2h(pv[0],  pv[1]),  d01 = pk2h(pv[2],  pv[3]);  \
      unsigned d10 = pk2h(pv[4],  pv[5]),  d11 = pk2h(pv[6],  pv[7]);  \
      unsigned d20 = pk2h(pv[8],  pv[9]),  d21 = pk2h(pv[10], pv[11]); \
      unsigned d30 = pk2h(pv[12], pv[13]), d31 = pk2h(pv[14], pv[15]); \
      unsigned rxA0 = (unsigned)__shfl_xor((int)(h ? d00 : d10), 32); \
      unsigned rxA1 = (unsigned)__shfl_xor((int)(h ? d01 : d11), 32); \
      unsigned rxB0 = (unsigned)__shfl_xor((int)(h ? d20 : d30), 32); \
      unsigned rxB1 = (unsigned)__shfl_xor((int)(h ? d21 : d31), 32); \
      unsigned o00 = h ? d10 : d00, o01 = h ? d11 : d01; \
      unsigned o10 = h ? d30 : d20, o11 = h ? d31 : d21; \
      unsigned fr0[4] = { h ? rxA0 : o00, h ? rxA1 : o01, \
                          h ? o00 : rxA0, h ? o01 : rxA1 }; \
      unsigned fr1[4] = { h ? rxB0 : o10, h ? rxB1 : o11, \
                          h ? o10 : rxB0, h ? o11 : rxB1 }; \
      f16x8 pb0, pb1; \
      __builtin_memcpy(&pb0, fr0, 16); __builtin_memcpy(&pb1, fr1, 16); \
      f16x8 vf0 = *reinterpret_cast<const f16x8*>(&Vt[cur][l31][(c)*32 + h*8]); \
      f16x8 vf1 = *reinterpret_cast<const f16x8*>(&Vt[cur][l31][(c)*32 + 16 + h*8]); \
      __builtin_amdgcn_s_setprio(1); \
      oacc = __builtin_amdgcn_mfma_f32_32x32x16_f16(vf0, pb0, oacc, 0, 0, 0); \
      oacc = __builtin_amdgcn_mfma_f32_32x32x16_f16(vf1, pb1, oacc, 0, 0, 0); \
      __builtin_amdgcn_s_setprio(0); }
    PVCHUNK(s0, 0, oaccA)
    PVCHUNK(s1, 1, oaccB)
    PVCHUNK(s2, 2, oaccA)
    PVCHUNK(s3, 3, oaccB)
    #undef PVCHUNK
    lsum += ls;

    if (kt + 128 < NSEQ) WRITET(cur ^ 1);  // vmcnt wait hidden by compute
    __syncthreads();
    cur ^= 1;
  }

  // cross-half l sum, then lane-local epilogue
  lsum += __shfl_xor(lsum, 32);
  float inv = 1.f / lsum;
  f16* op = O + (size_t)(q0 + l31) * HV + hd * HD;
  #pragma unroll
  for (int g = 0; g < 4; g++) {            // dims 8g+4h+{0..3}
    f16 ob[4];
    #pragma unroll
    for (int r = 0; r < 4; r++)
      ob[r] = (f16)((oaccA[4*g + r] + oaccB[4*g + r]) * inv);
    uint2 u; __builtin_memcpy(&u, ob, 8);
    *reinterpret_cast<uint2*>(op + 8*g + 4*h) = u;
  }
}

// ------------- layernorm (dim 1, ddof=1, no eps) + f16 copy ----------------
__global__ __launch_bounds__(256) void ln_kernel(const float* in, float* out,
                                                 f16* __restrict__ outh){
  __shared__ float sm[8];
  int row = blockIdx.x, tid = threadIdx.x;
  float4 x = reinterpret_cast<const float4*>(in + (size_t)row * EMB)[tid];
  float s = x.x + x.y + x.z + x.w;
  #pragma unroll
  for (int o = 32; o > 0; o >>= 1) s += __shfl_down(s, o);
  int wid = tid >> 6, lane = tid & 63;
  if (lane == 0) sm[wid] = s;
  __syncthreads();
  float mean = (sm[0] + sm[1] + sm[2] + sm[3]) * (1.f / EMB);
  float dx = x.x - mean, dy = x.y - mean, dz = x.z - mean, dw = x.w - mean;
  float qs = dx*dx + dy*dy + dz*dz + dw*dw;
  #pragma unroll
  for (int o = 32; o > 0; o >>= 1) qs += __shfl_down(qs, o);
  if (lane == 0) sm[4 + wid] = qs;
  __syncthreads();
  float var = (sm[4] + sm[5] + sm[6] + sm[7]) * (1.f / (EMB - 1));
  float inv = rsqrtf(var);
  float4 y = {dx * inv, dy * inv, dz * inv, dw * inv};
  reinterpret_cast<float4*>(out + (size_t)row * EMB)[tid] = y;
  f16 o4[4] = {(f16)y.x, (f16)y.y, (f16)y.z, (f16)y.w};
  uint2 u; __builtin_memcpy(&u, o4, 8);
  reinterpret_cast<uint2*>(outh + (size_t)row * EMB)[tid] = u;
}

extern "C" void kernel_launch(void* const* d_in, const int* in_sizes, int n_in,
                              void* d_out, int out_size, void* d_ws, size_t ws_size,
                              hipStream_t stream)
{
  const int*   ctx   = (const int*)d_in[0];
  const float* table = (const float*)d_in[1];
  const float* pos   = (const float*)d_in[2];
  const float* Wq    = (const float*)d_in[3];
  const float* Wk    = (const float*)d_in[4];
  const float* Wv    = (const float*)d_in[5];
  const float* Wo    = (const float*)d_in[6];
  const float* W1    = (const float*)d_in[7];
  const float* b1    = (const float*)d_in[8];
  const float* W2    = (const float*)d_in[9];
  const float* b2    = (const float*)d_in[10];

  float* z = (float*)d_out;                 // residual stream f32 [N][E]

  char* ws = (char*)d_ws;
  const size_t MB = 1u << 20;
  float* an   = (float*)(ws);
  f16*   anh  = (f16*)  (ws + 16 * MB);
  f16*   zh   = (f16*)  (ws + 24 * MB);
  f16*   qkvh = (f16*)  (ws + 32 * MB);
  f16*   Oh   = (f16*)  (ws + 44 * MB);
  f16*   h1h  = (f16*)  (ws + 32 * MB);
  f16*   wbuf = (f16*)  (ws + 48 * MB);

  embed_kernel<<<NSEQ * EMB / 4 / 256, 256, 0, stream>>>(ctx, table, pos, z, zh);

  for (int l = 0; l < NL; l++) {
    const float* wq  = Wq + (size_t)l * NH * EMB * HD;
    const float* wk  = Wk + (size_t)l * NH * EMB * HD;
    const float* wv  = Wv + (size_t)l * NH * EMB * HD;
    const float* wo  = Wo + (size_t)l * HV * EMB;
    const float* w1  = W1 + (size_t)l * EMB * FF;
    const float* bb1 = b1 + (size_t)l * FF;
    const float* w2  = W2 + (size_t)l * FF * EMB;
    const float* bb2 = b2 + (size_t)l * EMB;

    // qkvT rows: [0,512)=Q, [512,1024)=K, [1024,1536)=V
    convT_kernel<<<dim3(EMB/32, 1, NH), 256, 0, stream>>>(
        wq, wbuf + (size_t)0 * HV * EMB, EMB, HD, (long)EMB * HD, (long)HD * EMB);
    convT_kernel<<<dim3(EMB/32, 1, NH), 256, 0, stream>>>(
        wk, wbuf + (size_t)1 * HV * EMB, EMB, HD, (long)EMB * HD, (long)HD * EMB);
    convT_kernel<<<dim3(EMB/32, 1, NH), 256, 0, stream>>>(
        wv, wbuf + (size_t)2 * HV * EMB, EMB, HD, (long)EMB * HD, (long)HD * EMB);
    gemm_mfma<f16><<<dim3(QKVW/128, NSEQ/128), 256, 0, stream>>>(
        zh, wbuf, qkvh, nullptr, nullptr, EMB, QKVW, 0);

    attn_mfma<<<dim3(NSEQ/64, NH), 128, 0, stream>>>(qkvh, Oh);

    // z += Oh @ Wo : WoT [1024][512]
    convT_kernel<<<dim3(HV/32, EMB/32, 1), 256, 0, stream>>>(
        wo, wbuf, HV, EMB, 0, 0);
    gemm_mfma<float><<<dim3(EMB/128, NSEQ/128), 256, 0, stream>>>(
        Oh, wbuf, z, nullptr, z, HV, EMB, 0);
    ln_kernel<<<NSEQ, 256, 0, stream>>>(z, an, anh);

    // h1 = leaky(an @ W1 + b1) : W1T [2048][1024]
    convT_kernel<<<dim3(EMB/32, FF/32, 1), 256, 0, stream>>>(
        w1, wbuf, EMB, FF, 0, 0);
    gemm_mfma<f16><<<dim3(FF/128, NSEQ/128), 256, 0, stream>>>(
        anh, wbuf, h1h, bb1, nullptr, EMB, FF, 1);
    // z = h1 @ W2 + b2 + an : W2T [1024][2048]
    convT_kernel<<<dim3(FF/32, EMB/32, 1), 256, 0, stream>>>(
        w2, wbuf, FF, EMB, 0, 0);
    gemm_mfma<float><<<dim3(EMB/128, NSEQ/128), 256, 0, stream>>>(
        h1h, wbuf, z, bb2, an, FF, EMB, 0);
    ln_kernel<<<NSEQ, 256, 0, stream>>>(z, z, zh);
  }
}